// Round 16
// baseline (28.036 us; speedup 1.0000x reference)
//
#include <hip/hip_runtime.h>
#include <hip/hip_bf16.h>

// GetInitialSymbol: structured single-head cross-attention + residual.
//   q_i = 2*tgt[136+i]-1 (i<32); k_i = 2*mem[72+i]-1; v_{200+j} = mem[8+j]; v_265 = 1
//   fixed token: score=31, value=0.
// R15 (proven, 27.6us) + ONE change: 8-way key split in a 512-thread block
// (was 4-way/256t). Same rows/block (32), same 2 row-tiles/wave sharing K/V
// registers, same numeric path. 2 blocks/CU x 8 waves = 16 waves/CU (2x R15's
// occupancy) to hide the per-iteration serial chain. Merge tree: 8 -> 1.
#define B_   8
#define T_   2048
#define S_   2048
#define DIN  512
#define QOFF 136
#define KOFF 72
#define VSRC 8

typedef __attribute__((ext_vector_type(8))) short    bf16x8;
typedef __attribute__((ext_vector_type(8))) _Float16 f16x8;
typedef __attribute__((ext_vector_type(4))) float    f32x4;

constexpr int KSEC = 0;              // ushort offsets in ws (total 2 MB)
constexpr int VSEC = 524288;         // 8 batches x 65536
constexpr int BATCH_U = 65536;

constexpr int BLK = 512;             // 8 waves = 8 key segments of 256
constexpr int NGW = 8;               // 32-key groups per segment

__device__ __forceinline__ ushort f2b(float x) {
  __hip_bfloat16 h = __float2bfloat16(x);
  return __builtin_bit_cast(ushort, h);
}
__device__ __forceinline__ ushort f2h(float x) {
  return __builtin_bit_cast(ushort, (_Float16)x);
}

// ---------- kernel 1: K/V -> fragment-ordered fp16/bf16 in ws (unchanged) ----------
__global__ __launch_bounds__(256)
void preproc(const float* __restrict__ mem, ushort* __restrict__ ws) {
  const int t    = threadIdx.x;
  const int b    = blockIdx.x >> 5;
  const int key0 = (blockIdx.x & 31) * 64;
  const float*  mbase = mem + (size_t)b * S_ * DIN;
  ushort* wk = ws + KSEC + (size_t)b * BATCH_U;
  ushort* wv = ws + VSEC + (size_t)b * BATCH_U;

  #pragma unroll
  for (int rep = 0; rep < 2; ++rep) {
    const int cid = t + 256 * rep;
    const int key = cid >> 3, c = cid & 7;
    const float4 k4 = *(const float4*)(mbase + (size_t)(key0 + key) * DIN + KOFF + 4 * c);
    const float kf[4] = {k4.x, k4.y, k4.z, k4.w};
    ushort kh[4];
    #pragma unroll
    for (int e = 0; e < 4; ++e) kh[e] = f2h(2.f * kf[e] - 1.f);
    const int gkey = key0 + key;
    const int pos  = (gkey >> 4) * 512 + ((gkey & 15) + 16 * (c >> 1)) * 8 + 4 * (c & 1);
    *(uint2*)(wk + pos) = *(const uint2*)kh;
  }

  const int ch = t & 31, h = t >> 5;
  float vv[8];
  #pragma unroll
  for (int r = 0; r < 8; ++r)
    vv[r] = mbase[(size_t)(key0 + 8 * h + r) * DIN + VSRC + ch];
  ushort vb[8];
  #pragma unroll
  for (int r = 0; r < 8; ++r) vb[r] = f2b(vv[r]);
  #pragma unroll
  for (int half = 0; half < 2; ++half) {
    const int key = key0 + 8 * h + 4 * half;
    const int pos = (key >> 5) * 1024 + (ch >> 4) * 512
                  + ((ch & 15) + 16 * ((key >> 2) & 3)) * 8 + ((key >> 4) & 1) * 4;
    *(uint2*)(wv + pos) = *(const uint2*)&vb[half * 4];
  }
}

// ---------- merge helpers (per-rt pair, slot = 1280 floats) ----------
__device__ __forceinline__ void mwrite(float* d, int lane, const float* m,
                                       const float* ls, const f32x4 o0[2],
                                       const f32x4 o1[2]) {
  #pragma unroll
  for (int rt = 0; rt < 2; ++rt) {
    float* dr = d + rt * 640;
    dr[lane] = m[rt];
    dr[64 + lane] = ls[rt];
    #pragma unroll
    for (int i = 0; i < 4; ++i) {
      dr[128 + i * 64 + lane] = o0[rt][i];
      dr[384 + i * 64 + lane] = o1[rt][i];
    }
  }
}
__device__ __forceinline__ void mread(const float* s, int lane, float* m,
                                      float* ls, f32x4 o0[2], f32x4 o1[2]) {
  #pragma unroll
  for (int rt = 0; rt < 2; ++rt) {
    const float* sr = s + rt * 640;
    const float m1 = sr[lane], l1 = sr[64 + lane];
    const float mn = fmaxf(m[rt], m1);
    const float sa = __expf(m[rt] - mn), sb = __expf(m1 - mn);
    ls[rt] = ls[rt] * sa + l1 * sb;
    #pragma unroll
    for (int i = 0; i < 4; ++i) {
      o0[rt][i] = o0[rt][i] * sa + sr[128 + i * 64 + lane] * sb;
      o1[rt][i] = o1[rt][i] * sa + sr[384 + i * 64 + lane] * sb;
    }
    m[rt] = mn;
  }
}

// ---------- kernel 2: flash attention, 8-way key split, 2 row-tiles/wave ----------
__global__ __launch_bounds__(BLK, 4)
void attn_main(const float* __restrict__ tgt, const ushort* __restrict__ ws,
               float* __restrict__ out) {
  __shared__ float msl[4 * 1280 + 2 * 561];   // 4 merge slots + results (~25 KB)

  const int tid  = threadIdx.x;
  const int lane = tid & 63;
  const int wv   = tid >> 6;             // key segment 0..7
  const int Q    = lane >> 4;
  const int r15  = lane & 15;

  // XCD swizzle: batch == XCD (ws fragments, 256 KB/batch, stay L2-hot)
  const int o  = (blockIdx.x & 7) * 64 + (blockIdx.x >> 3);
  const int b  = o >> 6;
  const int t0 = (o & 63) * 32;

  const ushort* wsK = ws + KSEC + (size_t)b * BATCH_U;
  const ushort* wsV = ws + VSEC + (size_t)b * BATCH_U;
  const size_t  base = (size_t)(b * T_ + t0) * DIN;

  // P fragments (fp16), rt = 0,1: element j of lane = p[qrow=rt*16+r15][8Q+j]
  f16x8 pf[2];
  #pragma unroll
  for (int rt = 0; rt < 2; ++rt) {
    const float* tr = tgt + base + (size_t)(rt * 16 + r15) * DIN + QOFF + 8 * Q;
    const float4 qa = *(const float4*)tr;
    const float4 qb = *(const float4*)(tr + 4);
    const float pv[8] = {qa.x, qa.y, qa.z, qa.w, qb.x, qb.y, qb.z, qb.w};
    #pragma unroll
    for (int e = 0; e < 8; ++e) pf[rt][e] = (_Float16)(2.f * pv[e] - 1.f);
  }

  float m[2]  = {31.f, 31.f};            // fixed token score (exact)
  float ls[2];
  ls[0] = ls[1] = (Q == 0 && wv == 0) ? 1.f : 0.f;   // its exp, once per row
  f32x4 oc0[2] = {{0.f, 0.f, 0.f, 0.f}, {0.f, 0.f, 0.f, 0.f}};
  f32x4 oc1[2] = {{0.f, 0.f, 0.f, 0.f}, {0.f, 0.f, 0.f, 0.f}};

  // K/V register staging, 2 groups in flight; indices compile-time static.
  // Segment = 256 keys = 16 K-tiles (16 keys) = 8 V-groups (32 keys).
  bf16x8 stg[2][4];
  #define ISSUE(g, pb)                                                         \
    { const int ki = (wv * 16 + 2 * (g)) * 512 + lane * 8;                     \
      stg[pb][0] = *(const bf16x8*)(wsK + ki);                                 \
      stg[pb][1] = *(const bf16x8*)(wsK + ki + 512);                           \
      const int vi = (wv * NGW + (g)) * 1024 + lane * 8;                       \
      stg[pb][2] = *(const bf16x8*)(wsV + vi);                                 \
      stg[pb][3] = *(const bf16x8*)(wsV + vi + 512); }

  // Interleaved residual copy: 32 rows x 128 float4 = 4096 = 8 chunks of 512.
  f32x4 cp[2];
  int cpr[2], cpc[2];
  #define CLOAD(c, pb)                                                         \
    { const int vid = (c) * BLK + tid;                                         \
      cpr[pb] = vid >> 7; cpc[pb] = vid & 127;                                 \
      cp[pb] = *(const f32x4*)(tgt + base + (size_t)cpr[pb] * DIN + cpc[pb] * 4); }
  #define CSTORE(pb)                                                           \
    { const int cc = cpc[pb];                                                  \
      if (!((cc >= 50 && cc < 58) || cc == 66))                                \
        *(f32x4*)(out + base + (size_t)cpr[pb] * DIN + cc * 4) = cp[pb]; }

  ISSUE(0, 0)
  ISSUE(1, 1)
  CLOAD(0, 0)

  #pragma unroll
  for (int g = 0; g < NGW; ++g) {
    const int pb = g & 1;
    // copy pipeline: store chunk g-1, load chunk g (8 chunks over 8 groups)
    if (g >= 1)          CSTORE((g - 1) & 1)
    if (g >= 1 && g < 8) CLOAD(g, g & 1)

    const f16x8  k0 = __builtin_bit_cast(f16x8, stg[pb][0]);
    const f16x8  k1 = __builtin_bit_cast(f16x8, stg[pb][1]);
    const bf16x8 v0 = stg[pb][2];
    const bf16x8 v1 = stg[pb][3];

    if (g + 2 < NGW) ISSUE(g + 2, pb)   // prefetch while softmax+PV run

    #pragma unroll
    for (int rt = 0; rt < 2; ++rt) {
      // scores: C elem r of lane = score[key = 32g + 16*mt + 4Q + r][qrow]
      f32x4 c0 = {0.f, 0.f, 0.f, 0.f}, c1 = {0.f, 0.f, 0.f, 0.f};
      c0 = __builtin_amdgcn_mfma_f32_16x16x32_f16(k0, pf[rt], c0, 0, 0, 0);
      c1 = __builtin_amdgcn_mfma_f32_16x16x32_f16(k1, pf[rt], c1, 0, 0, 0);

      // online softmax, row-uniform max (shfl over Q groups), defer-threshold 8
      float gm = fmaxf(fmaxf(fmaxf(c0[0], c0[1]), fmaxf(c0[2], c0[3])),
                       fmaxf(fmaxf(c1[0], c1[1]), fmaxf(c1[2], c1[3])));
      gm = fmaxf(gm, __shfl_xor(gm, 16));
      gm = fmaxf(gm, __shfl_xor(gm, 32));
      if (__any(gm > m[rt] + 8.f)) {
        const float mn  = gm;
        const float scl = __expf(m[rt] - fmaxf(m[rt], mn));
        const float mx  = fmaxf(m[rt], mn);
        m[rt] = mx;
        ls[rt] *= scl;
        #pragma unroll
        for (int i = 0; i < 4; ++i) { oc0[rt][i] *= scl; oc1[rt][i] *= scl; }
      }

      // W frag: slot j <-> key (j>>2)*16 + 4Q + (j&3) (same bijection as V frag)
      bf16x8 wf;
      float wsum = 0.f;
      #pragma unroll
      for (int j = 0; j < 8; ++j) {
        const float w = __expf(((j < 4) ? c0[j & 3] : c1[j & 3]) - m[rt]);
        wsum += w;
        wf[j] = (short)f2b(w);
      }
      ls[rt] += wsum;

      oc0[rt] = __builtin_amdgcn_mfma_f32_16x16x32_bf16(v0, wf, oc0[rt], 0, 0, 0);
      oc1[rt] = __builtin_amdgcn_mfma_f32_16x16x32_bf16(v1, wf, oc1[rt], 0, 0, 0);
    }
  }
  CSTORE(7 & 1)                          // drain last copy chunk
  #undef ISSUE
  #undef CLOAD
  #undef CSTORE

  // ---- merge 8 segments -> wave 0 (3 rounds, 4 slots max)
  if (wv >= 4) mwrite(msl + (wv - 4) * 1280, lane, m, ls, oc0, oc1);
  __syncthreads();
  if (wv < 4) mread(msl + wv * 1280, lane, m, ls, oc0, oc1);
  __syncthreads();
  if (wv >= 2 && wv < 4) mwrite(msl + (wv - 2) * 1280, lane, m, ls, oc0, oc1);
  __syncthreads();
  if (wv < 2) mread(msl + wv * 1280, lane, m, ls, oc0, oc1);
  __syncthreads();
  if (wv == 1) mwrite(msl, lane, m, ls, oc0, oc1);
  __syncthreads();
  float* olds = msl + 4 * 1280;
  if (wv == 0) {
    mread(msl, lane, m, ls, oc0, oc1);
    #pragma unroll
    for (int rt = 0; rt < 2; ++rt) {
      float t2 = ls[rt] + __shfl_xor(ls[rt], 16);   // sum across Q-groups
      const float lt  = t2 + __shfl_xor(t2, 32);
      const float inv = 1.f / lt;
      #pragma unroll
      for (int i = 0; i < 4; ++i) {
        olds[rt * 561 + (4 * Q + i) * 17 + r15]      = oc0[rt][i] * inv;
        olds[rt * 561 + (16 + 4 * Q + i) * 17 + r15] = oc1[rt][i] * inv;
      }
      if (Q == 0) olds[rt * 561 + 32 * 17 + r15] = 1.f - __expf(31.f - m[rt]) * inv;
    }
  }
  __syncthreads();

  // ---- attn-touched float4s: 32 rows x 9 (c4 50..57, 66) = 288
  if (tid < 288) {
    const int row = tid / 9, j = tid - row * 9;
    const int rt = row >> 4, rr = row & 15;
    const int c4i = (j < 8) ? (50 + j) : 66;
    const size_t off = base + (size_t)row * DIN + c4i * 4;
    float4 ov = *(const float4*)(tgt + off);
    if (j < 8) {
      ov.x += olds[rt * 561 + (4 * j + 0) * 17 + rr];
      ov.y += olds[rt * 561 + (4 * j + 1) * 17 + rr];
      ov.z += olds[rt * 561 + (4 * j + 2) * 17 + rr];
      ov.w += olds[rt * 561 + (4 * j + 3) * 17 + rr];
    } else {
      ov.y += olds[rt * 561 + 32 * 17 + rr];       // channel 265
    }
    *(float4*)(out + off) = ov;
  }
}

extern "C" void kernel_launch(void* const* d_in, const int* in_sizes, int n_in,
                              void* d_out, int out_size, void* d_ws, size_t ws_size,
                              hipStream_t stream) {
  const float* tgt = (const float*)d_in[0];
  const float* mem = (const float*)d_in[1];
  ushort* ws = (ushort*)d_ws;            // needs 2 MB
  float* out = (float*)d_out;
  preproc<<<dim3(256), dim3(256), 0, stream>>>(mem, ws);
  attn_main<<<dim3(B_ * (T_ / 32)), dim3(BLK), 0, stream>>>(tgt, ws, out);
}

// Round 17
// 27.437 us; speedup vs baseline: 1.0218x; 1.0218x over previous
//
#include <hip/hip_runtime.h>
#include <hip/hip_bf16.h>

// GetInitialSymbol: structured single-head cross-attention + residual.
//   q_i = 2*tgt[136+i]-1 (i<32); k_i = 2*mem[72+i]-1; v_{200+j} = mem[8+j]; v_265 = 1
//   fixed token: score=31, value=0.
// FINAL (= Round 15, best proven at 27.6 us): preproc converts K'->fp16 /
// V->bf16 into exact MFMA fragment order in ws; attn_main is a register-staged
// flash attention, 4-way key split, 2 row-tiles/wave sharing K/V registers,
// tgt->out residual copy interleaved in the hot loop.
// R16 (2x occupancy) regressed -> latency-chain floor reached, not occupancy.
#define B_   8
#define T_   2048
#define S_   2048
#define DIN  512
#define QOFF 136
#define KOFF 72
#define VSRC 8

typedef __attribute__((ext_vector_type(8))) short    bf16x8;
typedef __attribute__((ext_vector_type(8))) _Float16 f16x8;
typedef __attribute__((ext_vector_type(4))) float    f32x4;

constexpr int KSEC = 0;              // ushort offsets in ws (total 2 MB)
constexpr int VSEC = 524288;         // 8 batches x 65536
constexpr int BATCH_U = 65536;

constexpr int BLK = 256;             // 4 waves = 4 key segments of 512
constexpr int NGW = 16;              // 32-key groups per segment

__device__ __forceinline__ ushort f2b(float x) {
  __hip_bfloat16 h = __float2bfloat16(x);
  return __builtin_bit_cast(ushort, h);
}
__device__ __forceinline__ ushort f2h(float x) {
  return __builtin_bit_cast(ushort, (_Float16)x);
}

// ---------- kernel 1: K/V -> fragment-ordered fp16/bf16 in ws ----------
__global__ __launch_bounds__(256)
void preproc(const float* __restrict__ mem, ushort* __restrict__ ws) {
  const int t    = threadIdx.x;
  const int b    = blockIdx.x >> 5;
  const int key0 = (blockIdx.x & 31) * 64;
  const float*  mbase = mem + (size_t)b * S_ * DIN;
  ushort* wk = ws + KSEC + (size_t)b * BATCH_U;
  ushort* wv = ws + VSEC + (size_t)b * BATCH_U;

  #pragma unroll
  for (int rep = 0; rep < 2; ++rep) {
    const int cid = t + 256 * rep;
    const int key = cid >> 3, c = cid & 7;
    const float4 k4 = *(const float4*)(mbase + (size_t)(key0 + key) * DIN + KOFF + 4 * c);
    const float kf[4] = {k4.x, k4.y, k4.z, k4.w};
    ushort kh[4];
    #pragma unroll
    for (int e = 0; e < 4; ++e) kh[e] = f2h(2.f * kf[e] - 1.f);
    const int gkey = key0 + key;
    const int pos  = (gkey >> 4) * 512 + ((gkey & 15) + 16 * (c >> 1)) * 8 + 4 * (c & 1);
    *(uint2*)(wk + pos) = *(const uint2*)kh;
  }

  const int ch = t & 31, h = t >> 5;
  float vv[8];
  #pragma unroll
  for (int r = 0; r < 8; ++r)
    vv[r] = mbase[(size_t)(key0 + 8 * h + r) * DIN + VSRC + ch];
  ushort vb[8];
  #pragma unroll
  for (int r = 0; r < 8; ++r) vb[r] = f2b(vv[r]);
  #pragma unroll
  for (int half = 0; half < 2; ++half) {
    const int key = key0 + 8 * h + 4 * half;
    const int pos = (key >> 5) * 1024 + (ch >> 4) * 512
                  + ((ch & 15) + 16 * ((key >> 2) & 3)) * 8 + ((key >> 4) & 1) * 4;
    *(uint2*)(wv + pos) = *(const uint2*)&vb[half * 4];
  }
}

// ---------- merge helpers (per-rt pair, slot = 1280 floats) ----------
__device__ __forceinline__ void mwrite(float* d, int lane, const float* m,
                                       const float* ls, const f32x4 o0[2],
                                       const f32x4 o1[2]) {
  #pragma unroll
  for (int rt = 0; rt < 2; ++rt) {
    float* dr = d + rt * 640;
    dr[lane] = m[rt];
    dr[64 + lane] = ls[rt];
    #pragma unroll
    for (int i = 0; i < 4; ++i) {
      dr[128 + i * 64 + lane] = o0[rt][i];
      dr[384 + i * 64 + lane] = o1[rt][i];
    }
  }
}
__device__ __forceinline__ void mread(const float* s, int lane, float* m,
                                      float* ls, f32x4 o0[2], f32x4 o1[2]) {
  #pragma unroll
  for (int rt = 0; rt < 2; ++rt) {
    const float* sr = s + rt * 640;
    const float m1 = sr[lane], l1 = sr[64 + lane];
    const float mn = fmaxf(m[rt], m1);
    const float sa = __expf(m[rt] - mn), sb = __expf(m1 - mn);
    ls[rt] = ls[rt] * sa + l1 * sb;
    #pragma unroll
    for (int i = 0; i < 4; ++i) {
      o0[rt][i] = o0[rt][i] * sa + sr[128 + i * 64 + lane] * sb;
      o1[rt][i] = o1[rt][i] * sa + sr[384 + i * 64 + lane] * sb;
    }
    m[rt] = mn;
  }
}

// ---------- kernel 2: flash attention, 2 row-tiles/wave, shared K/V regs ----------
__global__ __launch_bounds__(BLK, 4)
void attn_main(const float* __restrict__ tgt, const ushort* __restrict__ ws,
               float* __restrict__ out) {
  __shared__ float msl[3 * 1280 + 2 * 561];   // 3 merge slots + results (~20 KB)

  const int tid  = threadIdx.x;
  const int lane = tid & 63;
  const int wv   = tid >> 6;             // key segment 0..3
  const int Q    = lane >> 4;
  const int r15  = lane & 15;

  // XCD swizzle: batch == XCD (ws fragments, 256 KB/batch, stay L2-hot)
  const int o  = (blockIdx.x & 7) * 64 + (blockIdx.x >> 3);
  const int b  = o >> 6;
  const int t0 = (o & 63) * 32;

  const ushort* wsK = ws + KSEC + (size_t)b * BATCH_U;
  const ushort* wsV = ws + VSEC + (size_t)b * BATCH_U;
  const size_t  base = (size_t)(b * T_ + t0) * DIN;

  // P fragments (fp16), rt = 0,1: element j of lane = p[qrow=rt*16+r15][8Q+j]
  f16x8 pf[2];
  #pragma unroll
  for (int rt = 0; rt < 2; ++rt) {
    const float* tr = tgt + base + (size_t)(rt * 16 + r15) * DIN + QOFF + 8 * Q;
    const float4 qa = *(const float4*)tr;
    const float4 qb = *(const float4*)(tr + 4);
    const float pv[8] = {qa.x, qa.y, qa.z, qa.w, qb.x, qb.y, qb.z, qb.w};
    #pragma unroll
    for (int e = 0; e < 8; ++e) pf[rt][e] = (_Float16)(2.f * pv[e] - 1.f);
  }

  float m[2]  = {31.f, 31.f};            // fixed token score (exact)
  float ls[2];
  ls[0] = ls[1] = (Q == 0 && wv == 0) ? 1.f : 0.f;   // its exp, once per row
  f32x4 oc0[2] = {{0.f, 0.f, 0.f, 0.f}, {0.f, 0.f, 0.f, 0.f}};
  f32x4 oc1[2] = {{0.f, 0.f, 0.f, 0.f}, {0.f, 0.f, 0.f, 0.f}};

  // K/V register staging, 2 groups in flight; indices compile-time static.
  bf16x8 stg[2][4];
  #define ISSUE(g, pb)                                                         \
    { const int ki = (wv * 32 + 2 * (g)) * 512 + lane * 8;                     \
      stg[pb][0] = *(const bf16x8*)(wsK + ki);                                 \
      stg[pb][1] = *(const bf16x8*)(wsK + ki + 512);                           \
      const int vi = (wv * NGW + (g)) * 1024 + lane * 8;                       \
      stg[pb][2] = *(const bf16x8*)(wsV + vi);                                 \
      stg[pb][3] = *(const bf16x8*)(wsV + vi + 512); }

  // Interleaved residual copy: 32 rows x 128 float4 = 4096 = 16 chunks of 256.
  f32x4 cp[2];
  int cpr[2], cpc[2];
  #define CLOAD(c, pb)                                                         \
    { const int vid = (c) * BLK + tid;                                         \
      cpr[pb] = vid >> 7; cpc[pb] = vid & 127;                                 \
      cp[pb] = *(const f32x4*)(tgt + base + (size_t)cpr[pb] * DIN + cpc[pb] * 4); }
  #define CSTORE(pb)                                                           \
    { const int cc = cpc[pb];                                                  \
      if (!((cc >= 50 && cc < 58) || cc == 66))                                \
        *(f32x4*)(out + base + (size_t)cpr[pb] * DIN + cc * 4) = cp[pb]; }

  ISSUE(0, 0)
  ISSUE(1, 1)
  CLOAD(0, 0)

  #pragma unroll
  for (int g = 0; g < NGW; ++g) {
    const int pb = g & 1;
    // copy pipeline: store chunk g-1, load chunk g (16 chunks over 16 groups)
    if (g >= 1)           CSTORE((g - 1) & 1)
    if (g >= 1 && g < 16) CLOAD(g, g & 1)

    const f16x8  k0 = __builtin_bit_cast(f16x8, stg[pb][0]);
    const f16x8  k1 = __builtin_bit_cast(f16x8, stg[pb][1]);
    const bf16x8 v0 = stg[pb][2];
    const bf16x8 v1 = stg[pb][3];

    if (g + 2 < NGW) ISSUE(g + 2, pb)   // prefetch while softmax+PV run

    #pragma unroll
    for (int rt = 0; rt < 2; ++rt) {
      // scores: C elem r of lane = score[key = 32g + 16*mt + 4Q + r][qrow]
      f32x4 c0 = {0.f, 0.f, 0.f, 0.f}, c1 = {0.f, 0.f, 0.f, 0.f};
      c0 = __builtin_amdgcn_mfma_f32_16x16x32_f16(k0, pf[rt], c0, 0, 0, 0);
      c1 = __builtin_amdgcn_mfma_f32_16x16x32_f16(k1, pf[rt], c1, 0, 0, 0);

      // online softmax, row-uniform max (shfl over Q groups), defer-threshold 8
      float gm = fmaxf(fmaxf(fmaxf(c0[0], c0[1]), fmaxf(c0[2], c0[3])),
                       fmaxf(fmaxf(c1[0], c1[1]), fmaxf(c1[2], c1[3])));
      gm = fmaxf(gm, __shfl_xor(gm, 16));
      gm = fmaxf(gm, __shfl_xor(gm, 32));
      if (__any(gm > m[rt] + 8.f)) {
        const float mn  = gm;
        const float scl = __expf(m[rt] - fmaxf(m[rt], mn));
        const float mx  = fmaxf(m[rt], mn);
        m[rt] = mx;
        ls[rt] *= scl;
        #pragma unroll
        for (int i = 0; i < 4; ++i) { oc0[rt][i] *= scl; oc1[rt][i] *= scl; }
      }

      // W frag: slot j <-> key (j>>2)*16 + 4Q + (j&3) (same bijection as V frag)
      bf16x8 wf;
      float wsum = 0.f;
      #pragma unroll
      for (int j = 0; j < 8; ++j) {
        const float w = __expf(((j < 4) ? c0[j & 3] : c1[j & 3]) - m[rt]);
        wsum += w;
        wf[j] = (short)f2b(w);
      }
      ls[rt] += wsum;

      oc0[rt] = __builtin_amdgcn_mfma_f32_16x16x32_bf16(v0, wf, oc0[rt], 0, 0, 0);
      oc1[rt] = __builtin_amdgcn_mfma_f32_16x16x32_bf16(v1, wf, oc1[rt], 0, 0, 0);
    }
  }
  CSTORE(15 & 1)                         // drain last copy chunk
  #undef ISSUE
  #undef CLOAD
  #undef CSTORE

  // ---- merge 4 segments -> wave 0
  if (wv >= 2) mwrite(msl + (wv - 2) * 1280, lane, m, ls, oc0, oc1);
  __syncthreads();
  if (wv < 2) mread(msl + wv * 1280, lane, m, ls, oc0, oc1);
  __syncthreads();
  if (wv == 1) mwrite(msl, lane, m, ls, oc0, oc1);
  __syncthreads();
  float* olds = msl + 3 * 1280;
  if (wv == 0) {
    mread(msl, lane, m, ls, oc0, oc1);
    #pragma unroll
    for (int rt = 0; rt < 2; ++rt) {
      float t2 = ls[rt] + __shfl_xor(ls[rt], 16);   // sum across Q-groups
      const float lt  = t2 + __shfl_xor(t2, 32);
      const float inv = 1.f / lt;
      #pragma unroll
      for (int i = 0; i < 4; ++i) {
        olds[rt * 561 + (4 * Q + i) * 17 + r15]      = oc0[rt][i] * inv;
        olds[rt * 561 + (16 + 4 * Q + i) * 17 + r15] = oc1[rt][i] * inv;
      }
      if (Q == 0) olds[rt * 561 + 32 * 17 + r15] = 1.f - __expf(31.f - m[rt]) * inv;
    }
  }
  __syncthreads();

  // ---- attn-touched float4s: 32 rows x 9 (c4 50..57, 66) = 288
  #pragma unroll
  for (int k = 0; k < 2; ++k) {
    const int idx = tid + k * BLK;
    if (idx < 288) {
      const int row = idx / 9, j = idx - row * 9;
      const int rt = row >> 4, rr = row & 15;
      const int c4i = (j < 8) ? (50 + j) : 66;
      const size_t off = base + (size_t)row * DIN + c4i * 4;
      float4 ov = *(const float4*)(tgt + off);
      if (j < 8) {
        ov.x += olds[rt * 561 + (4 * j + 0) * 17 + rr];
        ov.y += olds[rt * 561 + (4 * j + 1) * 17 + rr];
        ov.z += olds[rt * 561 + (4 * j + 2) * 17 + rr];
        ov.w += olds[rt * 561 + (4 * j + 3) * 17 + rr];
      } else {
        ov.y += olds[rt * 561 + 32 * 17 + rr];       // channel 265
      }
      *(float4*)(out + off) = ov;
    }
  }
}

extern "C" void kernel_launch(void* const* d_in, const int* in_sizes, int n_in,
                              void* d_out, int out_size, void* d_ws, size_t ws_size,
                              hipStream_t stream) {
  const float* tgt = (const float*)d_in[0];
  const float* mem = (const float*)d_in[1];
  ushort* ws = (ushort*)d_ws;            // needs 2 MB
  float* out = (float*)d_out;
  preproc<<<dim3(256), dim3(256), 0, stream>>>(mem, ws);
  attn_main<<<dim3(B_ * (T_ / 32)), dim3(BLK), 0, stream>>>(tgt, ws, out);
}